// Round 6
// baseline (9936.741 us; speedup 1.0000x reference)
//
#include <hip/hip_runtime.h>

#define DMODEL 1024
#define DSTATE 16
#define DCONV  4
#define DINNER 2048
#define BSZ    2
#define LSEQ   2048
#define MTOT   (BSZ * LSEQ)   // 4096 rows for all GEMMs
#define NCH    64             // scan chunks per sequence
#define LC     (LSEQ / NCH)   // 32 timesteps per chunk
#define LOG2E  1.44269504088896f

typedef unsigned short u16;
typedef __attribute__((ext_vector_type(8))) short short8;           // 8 bf16 (MFMA A/B frag)
typedef __attribute__((ext_vector_type(8))) unsigned short u16x8;   // 16B bf16 chunk
typedef __attribute__((ext_vector_type(4))) float f32x4;            // MFMA C/D frag

// Fragment-tiled (FT) layout: matrix [R][K] stored as 1KB units of 16 rows x 32 k.
// unit = (r>>4)*(K>>5) + (k>>5); 16B chunk li = (r&15) | (((k>>3)&3)<<4);
// elem addr = unit*512 + li*8 + (k&7).  A wave's lane l loading 16B at
// unit*512 + l*8 gets exactly the mfma_16x16x32_bf16 A/B fragment
// (row = l&15, k = (l>>4)*8 + j) -- so GEMMs need no LDS and no barriers.

__device__ __forceinline__ float silu_f(float v) {
  return v * __builtin_amdgcn_rcpf(1.f + __builtin_amdgcn_exp2f(-v * LOG2E));
}

__device__ __forceinline__ u16 f2bf(float f) {   // RNE f32 -> bf16
  unsigned int u = __float_as_uint(f);
  u += 0x7FFF + ((u >> 16) & 1);
  return (u16)(u >> 16);
}
__device__ __forceinline__ float bf2f(u16 b) { return __uint_as_float(((unsigned int)b) << 16); }

// one 16B chunk of a f32->bf16 fragment-tiled cast. K8l = log2(K/8).
__device__ __forceinline__ void cast_ft_one(const float* __restrict__ s, u16* __restrict__ d,
                                            int i, int K8l) {
  const int ko = i & ((1 << K8l) - 1);
  const int r  = i >> K8l;
  const float4* sp = (const float4*)(s + ((size_t)r << (K8l + 3)) + ko * 8);
  const float4 v0 = sp[0], v1 = sp[1];
  const int NKT = 1 << (K8l - 2);
  const size_t unit = (size_t)(r >> 4) * NKT + (ko >> 2);
  const int li = (r & 15) | ((ko & 3) << 4);
  u16x8 o = { f2bf(v0.x), f2bf(v0.y), f2bf(v0.z), f2bf(v0.w),
              f2bf(v1.x), f2bf(v1.y), f2bf(v1.z), f2bf(v1.w) };
  *(u16x8*)(d + unit * 512 + li * 8) = o;
}

// x (4096x1024), W_in (4096x1024), W_dt (2048x2048), W_out (1024x2048) -> FT bf16
__global__ __launch_bounds__(256)
void cast4_ft(const float* __restrict__ x, u16* __restrict__ xd,
              const float* __restrict__ wi, u16* __restrict__ wid,
              const float* __restrict__ wd, u16* __restrict__ wdd,
              const float* __restrict__ wo, u16* __restrict__ wod) {
  int i = blockIdx.x * 256 + threadIdx.x;
  if (i < 524288)       cast_ft_one(x,  xd,  i,           7);
  else if (i < 1048576) cast_ft_one(wi, wid, i - 524288,  7);
  else if (i < 1572864) cast_ft_one(wd, wdd, i - 1048576, 8);
  else if (i < 1835008) cast_ft_one(wo, wod, i - 1572864, 8);
}

// C[M,N] = A[M,K] @ B[N,K]^T; A,B fragment-tiled bf16. One wave per block,
// 64x64 output tile, no LDS, no barriers: fragments load straight from global
// (coalesced 1KB per load), double-buffered 2 K-iters deep so the compiler can
// keep loads in flight across iterations (vmcnt(N), never a full drain).
// MODE 0: plain. MODE 1: softplus(C + bias[col]).  OBF: 1 -> bf16 C, 0 -> fp32 C.
template<int MODE, int OBF, int GM>
__global__ __launch_bounds__(64, 3)
void wgemm(const u16* __restrict__ A, const u16* __restrict__ B,
           const float* __restrict__ bias, void* __restrict__ Cv,
           int M, int N, int K) {
  const int lane = threadIdx.x;
  const int NKT = K >> 5;
  const int nbm = M >> 6, nbn = N >> 6;
  const int pid = blockIdx.x;
  const int npg = GM * nbn;
  const int fm  = (pid / npg) * GM;
  const int gsz = (nbm - fm < GM) ? (nbm - fm) : GM;
  const int bm  = fm + (pid % gsz);
  const int bn  = (pid % npg) / gsz;

  const u16* Ap[4];
  const u16* Bp[4];
#pragma unroll
  for (int t = 0; t < 4; ++t) {
    Ap[t] = A + ((size_t)(4 * bm + t) * NKT) * 512 + lane * 8;
    Bp[t] = B + ((size_t)(4 * bn + t) * NKT) * 512 + lane * 8;
  }
  const int NK = K >> 5;

  short8 af[2][4], bf[2][4];
#pragma unroll
  for (int t = 0; t < 4; ++t) {
    af[0][t] = *(const short8*)(Ap[t]);
    bf[0][t] = *(const short8*)(Bp[t]);
    af[1][t] = *(const short8*)(Ap[t] + 512);
    bf[1][t] = *(const short8*)(Bp[t] + 512);
  }

  f32x4 acc[4][4] = {};
#pragma unroll 2
  for (int kt = 0; kt < NK; ++kt) {
    const int cur = kt & 1;
#pragma unroll
    for (int ti = 0; ti < 4; ++ti)
#pragma unroll
      for (int tj = 0; tj < 4; ++tj)
        acc[ti][tj] = __builtin_amdgcn_mfma_f32_16x16x32_bf16(af[cur][ti], bf[cur][tj],
                                                              acc[ti][tj], 0, 0, 0);
    if (kt + 2 < NK) {
      const int off = (kt + 2) * 512;
#pragma unroll
      for (int t = 0; t < 4; ++t) {
        af[cur][t] = *(const short8*)(Ap[t] + off);
        bf[cur][t] = *(const short8*)(Bp[t] + off);
      }
    }
  }

  // C/D layout: col = lane&15, row = quad*4 + reg (m89/m91)
  const int quad = lane >> 4, l16 = lane & 15;
#pragma unroll
  for (int ti = 0; ti < 4; ++ti) {
    const int row0 = bm * 64 + 16 * ti + quad * 4;
#pragma unroll
    for (int tj = 0; tj < 4; ++tj) {
      const int col = bn * 64 + 16 * tj + l16;
      const float bv = (MODE == 1) ? bias[col] : 0.f;
#pragma unroll
      for (int i = 0; i < 4; ++i) {
        float v = acc[ti][tj][i] + bv;
        if (MODE == 1) v = (v > 20.f) ? v : __logf(1.f + __expf(v));   // softplus
        if (OBF) ((u16*)Cv)[(size_t)(row0 + i) * N + col] = f2bf(v);
        else     ((float*)Cv)[(size_t)(row0 + i) * N + col] = v;
      }
    }
  }
}

// depthwise causal conv1d (taps=4) + bias + SiLU; thread per (t, 8-channel octet).
// Dual write: row-major (for scan) + fragment-tiled (for GEMM2's A operand).
__global__ __launch_bounds__(256)
void conv_silu(const u16* __restrict__ xz, const float* __restrict__ conv_w,
               const float* __restrict__ conv_b, u16* __restrict__ xact_rm,
               u16* __restrict__ xact_ft) {
  const int i = blockIdx.x * 256 + threadIdx.x;  // MTOT * 256 octets = 2^20
  const int ko = i & 255;
  const int t  = (i >> 8) & (LSEQ - 1);
  const int b  = i >> 19;
  const int c  = ko << 3;
  float a[8];
  float4 w[8];
#pragma unroll
  for (int j = 0; j < 8; ++j) {
    a[j] = conv_b[c + j];
    w[j] = *(const float4*)(conv_w + (c + j) * DCONV);
  }
#pragma unroll
  for (int k = 0; k < DCONV; ++k) {
    const int tt = t + k - (DCONV - 1);
    if (tt >= 0) {
      const u16x8 v = *(const u16x8*)(xz + ((size_t)(b * LSEQ + tt) << 12) + c);
      const float wk[8] = { ((const float*)&w[0])[k], ((const float*)&w[1])[k],
                            ((const float*)&w[2])[k], ((const float*)&w[3])[k],
                            ((const float*)&w[4])[k], ((const float*)&w[5])[k],
                            ((const float*)&w[6])[k], ((const float*)&w[7])[k] };
#pragma unroll
      for (int j = 0; j < 8; ++j) a[j] = fmaf(bf2f(v[j]), wk[j], a[j]);
    }
  }
  u16x8 o;
#pragma unroll
  for (int j = 0; j < 8; ++j) o[j] = f2bf(silu_f(a[j]));
  const int m = b * LSEQ + t;
  *(u16x8*)(xact_rm + ((size_t)m << 11) + c) = o;
  const size_t unit = (size_t)(m >> 4) * 64 + (ko >> 2);     // NKT = 2048/32 = 64
  const int li = (m & 15) | ((ko & 3) << 4);
  *(u16x8*)(xact_ft + unit * 512 + li * 8) = o;
}

// ---- chunked parallel scan (exact decomposition of the linear recurrence) --

__global__ __launch_bounds__(256, 2)
void scan_pass1(const u16* __restrict__ dtb, const u16* __restrict__ xact,
                const float* __restrict__ A_log,
                float* __restrict__ hbuf, float* __restrict__ sumdt) {
  const int gid = blockIdx.x * 256 + threadIdx.x;  // 2^18 lanes
  const int c  = gid & (DINNER - 1);
  const int ch = (gid >> 11) & (NCH - 1);
  const int b  = gid >> 17;
  float a2[16];
#pragma unroll
  for (int s = 0; s < 16; ++s)
    a2[s] = -__expf(A_log[c * DSTATE + s]) * LOG2E;   // exp(dt*a) = exp2(dt*a2)
  const size_t base = ((size_t)(b * LSEQ + ch * LC) << 11) + c;
  float h[16] = {};
  float sd = 0.f;
  for (int j = 0; j < LC; j += 2) {
    const float dt0 = bf2f(dtb [base + ((size_t)j << 11)]);
    const float xv0 = bf2f(xact[base + ((size_t)j << 11)]);
    const float dt1 = bf2f(dtb [base + ((size_t)(j + 1) << 11)]);
    const float xv1 = bf2f(xact[base + ((size_t)(j + 1) << 11)]);
    const float dx0 = dt0 * xv0, dx1 = dt1 * xv1;
    sd += dt0 + dt1;
#pragma unroll
    for (int s = 0; s < 16; ++s)
      h[s] = fmaf(__builtin_amdgcn_exp2f(dt0 * a2[s]), h[s], dx0);
#pragma unroll
    for (int s = 0; s < 16; ++s)
      h[s] = fmaf(__builtin_amdgcn_exp2f(dt1 * a2[s]), h[s], dx1);
  }
  float4* ho = (float4*)&hbuf[(((size_t)(b * NCH + ch) * DINNER) + c) << 4];
#pragma unroll
  for (int q = 0; q < 4; ++q) {
    float4 v = { h[4 * q], h[4 * q + 1], h[4 * q + 2], h[4 * q + 3] };
    ho[q] = v;
  }
  sumdt[(size_t)(b * NCH + ch) * DINNER + c] = sd;
}

__global__ __launch_bounds__(256)
void scan_combine(float* __restrict__ hbuf, const float* __restrict__ sumdt,
                  const float* __restrict__ A_log) {
  const int gid = blockIdx.x * 256 + threadIdx.x;  // 2^16: b*32768 + c*16 + s
  const int s = gid & 15;
  const int c = (gid >> 4) & (DINNER - 1);
  const int b = gid >> 15;
  const float a2 = -__expf(A_log[c * DSTATE + s]) * LOG2E;
  float h = 0.f;
  for (int k = 0; k < NCH; ++k) {
    const size_t o = (((size_t)(b * NCH + k) * DINNER) + c) * 16 + s;
    const float he = hbuf[o];
    const float sd = sumdt[(size_t)(b * NCH + k) * DINNER + c];
    hbuf[o] = h;                          // h_start for chunk k
    h = fmaf(__builtin_amdgcn_exp2f(sd * a2), h, he);
  }
}

// Pass 3: re-scan from h_start; y = sum_s h + Dp*x; gate silu(z).
// yg is written FRAGMENT-TILED (it is GEMM3's A operand).
__global__ __launch_bounds__(256, 2)
void scan_pass3(const u16* __restrict__ dtb, const u16* __restrict__ xact,
                const u16* __restrict__ xz, const float* __restrict__ A_log,
                const float* __restrict__ Dp, const float* __restrict__ hbuf,
                u16* __restrict__ yg_ft) {
  const int gid = blockIdx.x * 256 + threadIdx.x;
  const int c  = gid & (DINNER - 1);
  const int ch = (gid >> 11) & (NCH - 1);
  const int b  = gid >> 17;
  float a2[16];
#pragma unroll
  for (int s = 0; s < 16; ++s)
    a2[s] = -__expf(A_log[c * DSTATE + s]) * LOG2E;
  const float dp = Dp[c];
  float h[16];
  const float4* hi = (const float4*)&hbuf[(((size_t)(b * NCH + ch) * DINNER) + c) << 4];
#pragma unroll
  for (int q = 0; q < 4; ++q) {
    float4 v = hi[q];
    h[4 * q] = v.x; h[4 * q + 1] = v.y; h[4 * q + 2] = v.z; h[4 * q + 3] = v.w;
  }
  const size_t base  = ((size_t)(b * LSEQ + ch * LC) << 11) + c;
  const size_t zbase = ((size_t)(b * LSEQ + ch * LC) << 12) + DINNER + c;
  // FT store: addr = (m>>4)*32768 + cpart + (m&15)*8, cpart per-lane constant
  const size_t cpart = (size_t)(c >> 5) * 512 + ((c >> 3) & 3) * 128 + (c & 7);
  const int m0 = b * LSEQ + ch * LC;
  for (int j = 0; j < LC; j += 2) {
    const float dt0 = bf2f(dtb [base + ((size_t)j << 11)]);
    const float xv0 = bf2f(xact[base + ((size_t)j << 11)]);
    const float zv0 = bf2f(xz[zbase + ((size_t)j << 12)]);
    const float dt1 = bf2f(dtb [base + ((size_t)(j + 1) << 11)]);
    const float xv1 = bf2f(xact[base + ((size_t)(j + 1) << 11)]);
    const float zv1 = bf2f(xz[zbase + ((size_t)(j + 1) << 12)]);
    const float dx0 = dt0 * xv0, dx1 = dt1 * xv1;
    float y0 = 0.f, y1 = 0.f;
#pragma unroll
    for (int s = 0; s < 16; ++s) {
      h[s] = fmaf(__builtin_amdgcn_exp2f(dt0 * a2[s]), h[s], dx0);
      y0 += h[s];
    }
#pragma unroll
    for (int s = 0; s < 16; ++s) {
      h[s] = fmaf(__builtin_amdgcn_exp2f(dt1 * a2[s]), h[s], dx1);
      y1 += h[s];
    }
    y0 = fmaf(dp, xv0, y0);
    y1 = fmaf(dp, xv1, y1);
    const int ma = m0 + j, mb = m0 + j + 1;
    yg_ft[(size_t)(ma >> 4) * 32768 + cpart + (ma & 15) * 8] = f2bf(y0 * silu_f(zv0));
    yg_ft[(size_t)(mb >> 4) * 32768 + cpart + (mb & 15) * 8] = f2bf(y1 * silu_f(zv1));
  }
}

extern "C" void kernel_launch(void* const* d_in, const int* in_sizes, int n_in,
                              void* d_out, int out_size, void* d_ws, size_t ws_size,
                              hipStream_t stream) {
  const float* x      = (const float*)d_in[0];
  const float* W_in   = (const float*)d_in[1];
  const float* conv_w = (const float*)d_in[2];
  const float* conv_b = (const float*)d_in[3];
  const float* A_log  = (const float*)d_in[4];
  const float* Dp     = (const float*)d_in[5];
  const float* W_dt   = (const float*)d_in[6];
  const float* b_dt   = (const float*)d_in[7];
  const float* W_out  = (const float*)d_in[8];
  float* out = (float*)d_out;

  // workspace (~141 MB)
  float* ws    = (float*)d_ws;
  float* hbuf  = ws;                                     // [B,NCH,D,16] f32 16 MB
  float* sumdt = hbuf + (size_t)BSZ * NCH * DINNER * 16; // 1 MB
  u16* xz      = (u16*)(sumdt + (size_t)BSZ * NCH * DINNER); // rm [4096,4096]  32 MB
  u16* dtb     = xz   + (size_t)MTOT * 2 * DINNER;       // rm [4096,2048]      16 MB
  u16* xbf     = dtb  + (size_t)MTOT * DINNER;           // FT x                 8 MB
  u16* wibf    = xbf  + (size_t)MTOT * DMODEL;           // FT W_in              8 MB
  u16* wdbf    = wibf + (size_t)2 * DINNER * DMODEL;     // FT W_dt              8 MB
  u16* wobf    = wdbf + (size_t)DINNER * DINNER;         // FT W_out             4 MB
  u16* xact_rm = wobf + (size_t)DMODEL * DINNER;         // rm x_act            16 MB
  u16* xact_ft = xact_rm + (size_t)MTOT * DINNER;        // FT x_act            16 MB
  u16* yg_ft   = xact_ft + (size_t)MTOT * DINNER;        // FT y_gated          16 MB

  const dim3 blk(256);

  // 0) casts to fragment-tiled bf16 (one dispatch)
  cast4_ft<<<1835008 / 256, blk, 0, stream>>>(x, xbf, W_in, wibf, W_dt, wdbf, W_out, wobf);

  // 1) xz = x @ W_in^T (bf16 rm out)
  wgemm<0, 1, 8><<<(MTOT / 64) * (2 * DINNER / 64), dim3(64), 0, stream>>>(
      xbf, wibf, nullptr, xz, MTOT, 2 * DINNER, DMODEL);
  // 2) x_act = silu(conv(x_proj) + conv_b); rm + FT
  conv_silu<<<(MTOT * 256) / 256, blk, 0, stream>>>(xz, conv_w, conv_b, xact_rm, xact_ft);
  // 3) dt = softplus(x_act @ W_dt^T + b_dt) (bf16 rm out)
  wgemm<1, 1, 8><<<(MTOT / 64) * (DINNER / 64), dim3(64), 0, stream>>>(
      xact_ft, wdbf, b_dt, dtb, MTOT, DINNER, DINNER);
  // 4) chunked selective scan + D skip + gate (yg FT out)
  scan_pass1<<<BSZ * NCH * DINNER / 256, blk, 0, stream>>>(dtb, xact_rm, A_log, hbuf, sumdt);
  scan_combine<<<BSZ * DINNER * 16 / 256, blk, 0, stream>>>(hbuf, sumdt, A_log);
  scan_pass3<<<BSZ * NCH * DINNER / 256, blk, 0, stream>>>(dtb, xact_rm, xz, A_log, Dp, hbuf, yg_ft);
  // 5) out = y_gated @ W_out^T (fp32 out)
  wgemm<0, 0, 8><<<(MTOT / 64) * (DMODEL / 64), dim3(64), 0, stream>>>(
      yg_ft, wobf, nullptr, out, MTOT, DMODEL, DINNER);
}

// Round 7
// 336.667 us; speedup vs baseline: 29.5150x; 29.5150x over previous
//
#include <hip/hip_runtime.h>

#define DMODEL 1024
#define DSTATE 16
#define DCONV  4
#define DINNER 2048
#define BSZ    2
#define LSEQ   2048
#define MTOT   (BSZ * LSEQ)   // 4096 rows for all GEMMs
#define NCH    64             // scan chunks per sequence
#define LC     (LSEQ / NCH)   // 32 timesteps per chunk
#define LOG2E  1.44269504088896f

typedef unsigned short u16;
typedef __attribute__((ext_vector_type(8))) short short8;           // 8 bf16 (MFMA A/B frag)
typedef __attribute__((ext_vector_type(8))) unsigned short u16x8;   // 16B bf16 chunk
typedef __attribute__((ext_vector_type(4))) float f32x4;            // MFMA C/D frag

__device__ __forceinline__ float silu_f(float v) {
  return v * __builtin_amdgcn_rcpf(1.f + __builtin_amdgcn_exp2f(-v * LOG2E));
}

__device__ __forceinline__ u16 f2bf(float f) {   // RNE f32 -> bf16
  unsigned int u = __float_as_uint(f);
  u += 0x7FFF + ((u >> 16) & 1);
  return (u16)(u >> 16);
}
__device__ __forceinline__ float bf2f(u16 b) { return __uint_as_float(((unsigned int)b) << 16); }

// async global->LDS, 16B/lane; LDS dest = wave-uniform base + lane*16 (m104)
__device__ __forceinline__ void gload_lds16(const u16* g, u16* l) {
  __builtin_amdgcn_global_load_lds((const __attribute__((address_space(1))) unsigned int*)g,
                                   (__attribute__((address_space(3))) unsigned int*)l, 16, 0, 0);
}

// All four f32->bf16 casts in one dispatch (x, W_in, W_dt, W_out), row-major
__global__ __launch_bounds__(256)
void cast4(const float4* __restrict__ s0, ushort4* __restrict__ d0, int n0,
           const float4* __restrict__ s1, ushort4* __restrict__ d1, int n1,
           const float4* __restrict__ s2, ushort4* __restrict__ d2, int n2,
           const float4* __restrict__ s3, ushort4* __restrict__ d3, int n3) {
  int i = blockIdx.x * 256 + threadIdx.x;
  const float4* s; ushort4* d;
  if (i < n0)                { s = s0; d = d0; }
  else if ((i -= n0) < n1)   { s = s1; d = d1; }
  else if ((i -= n1) < n2)   { s = s2; d = d2; }
  else if ((i -= n2) < n3)   { s = s3; d = d3; }
  else return;
  float4 v = s[i];
  ushort4 o = { f2bf(v.x), f2bf(v.y), f2bf(v.z), f2bf(v.w) };
  d[i] = o;
}

// C[M,N] = A[M,K] @ B[N,K]^T, bf16 inputs. 128x128 tile, BK=64, 4 waves,
// 4x4 mfma_16x16x32 tiles per wave x 2 k-steps = 32 MFMA between barriers
// (2x the m97 cadence -> half the barrier drains). LDS 2x16KB, row-major
// [row][64], 16B chunks XOR-swizzled by (row&7) -> <=2-way conflicts (free).
// 1-D grid, GROUP_M=4 panel swizzle (halved FETCH in r4).
// MODE 0: plain. MODE 1: softplus(C + bias[col]).  OBF: 1 -> bf16 C, 0 -> fp32 C.
template<int MODE, int OBF>
__global__ __launch_bounds__(256)
void hgemm64(const u16* __restrict__ A, const u16* __restrict__ B,
             const float* __restrict__ bias, void* __restrict__ Cv,
             int M, int N, int K) {
  __shared__ u16 As[128 * 64];   // 16 KB
  __shared__ u16 Bs[128 * 64];   // 16 KB
  const int tid  = threadIdx.x;
  const int lane = tid & 63;
  const int w    = tid >> 6;
  const int quad = lane >> 4;
  const int l16  = lane & 15;

  // GROUP_M=4 panel swizzle
  const int nbn = N >> 7, nbm = M >> 7;
  const int pid = blockIdx.x;
  const int npg = 4 * nbn;
  const int fm  = (pid / npg) * 4;
  const int gsz = (nbm - fm < 4) ? (nbm - fm) : 4;
  const int bm  = (fm + (pid % gsz)) << 7;
  const int bn  = ((pid % npg) / gsz) << 7;

  const int wm = (w & 1) * 64;
  const int wn = (w >> 1) * 64;

  // Staging: 16 segments of 1KB (8 rows x 128B); wave w fills segs 4w..4w+3
  // of both matrices. lane -> row_in_seg = l>>3, phys chunk p = l&7,
  // data chunk cd = p ^ (row&7)  (row&7 == row_in_seg since segs are 8-aligned).
  const int rseg = lane >> 3;
  const int cd   = (lane & 7) ^ rseg;
  const u16* Ag[4]; const u16* Bg[4]; u16* Al[4]; u16* Bl[4];
#pragma unroll
  for (int s = 0; s < 4; ++s) {
    const int sg = w * 4 + s;
    const int r  = sg * 8 + rseg;
    Ag[s] = A + (size_t)(bm + r) * K + (cd << 3);
    Bg[s] = B + (size_t)(bn + r) * K + (cd << 3);
    Al[s] = &As[sg << 9];
    Bl[s] = &Bs[sg << 9];
  }

  // Fragment pointers (K-invariant): row ra, k-chunk (quad + 4*ks) ^ (ra&7)
  const short8* Afp[4][2];
  const short8* Bfp[4][2];
#pragma unroll
  for (int t = 0; t < 4; ++t) {
    const int ra = wm + 16 * t + l16;
    const int rb = wn + 16 * t + l16;
#pragma unroll
    for (int ks = 0; ks < 2; ++ks) {
      Afp[t][ks] = (const short8*)&As[ra * 64 + (((quad + 4 * ks) ^ (ra & 7)) << 3)];
      Bfp[t][ks] = (const short8*)&Bs[rb * 64 + (((quad + 4 * ks) ^ (rb & 7)) << 3)];
    }
  }

  f32x4 acc[4][4] = {};

  for (int k0 = 0; k0 < K; k0 += 64) {
#pragma unroll
    for (int s = 0; s < 4; ++s) {
      gload_lds16(Ag[s], Al[s]);
      gload_lds16(Bg[s], Bl[s]);
      Ag[s] += 64; Bg[s] += 64;
    }
    __syncthreads();   // drain DMA before LDS reads
#pragma unroll
    for (int ks = 0; ks < 2; ++ks) {
      short8 af[4], bf[4];
#pragma unroll
      for (int t = 0; t < 4; ++t) { af[t] = *Afp[t][ks]; bf[t] = *Bfp[t][ks]; }
#pragma unroll
      for (int ti = 0; ti < 4; ++ti)
#pragma unroll
        for (int tj = 0; tj < 4; ++tj)
          acc[ti][tj] = __builtin_amdgcn_mfma_f32_16x16x32_bf16(af[ti], bf[tj],
                                                                acc[ti][tj], 0, 0, 0);
    }
    __syncthreads();
  }

  // C/D layout: col = lane&15, row = quad*4 + reg (m89/m91)
#pragma unroll
  for (int ti = 0; ti < 4; ++ti) {
    const int row0 = bm + wm + 16 * ti + quad * 4;
#pragma unroll
    for (int tj = 0; tj < 4; ++tj) {
      const int col = bn + wn + 16 * tj + l16;
      const float bv = (MODE == 1) ? bias[col] : 0.f;
#pragma unroll
      for (int i = 0; i < 4; ++i) {
        float v = acc[ti][tj][i] + bv;
        if (MODE == 1) v = (v > 20.f) ? v : __logf(1.f + __expf(v));   // softplus
        if (OBF) ((u16*)Cv)[(size_t)(row0 + i) * N + col] = f2bf(v);
        else     ((float*)Cv)[(size_t)(row0 + i) * N + col] = v;
      }
    }
  }
}

// depthwise causal conv1d (taps=4) + bias + SiLU; thread per (t, 8-channel octet)
__global__ __launch_bounds__(256)
void conv_silu(const u16* __restrict__ xz, const float* __restrict__ conv_w,
               const float* __restrict__ conv_b, u16* __restrict__ xact) {
  const int i = blockIdx.x * 256 + threadIdx.x;  // MTOT * 256 octets = 2^20
  const int ko = i & 255;
  const int t  = (i >> 8) & (LSEQ - 1);
  const int b  = i >> 19;
  const int c  = ko << 3;
  float a[8];
  float4 w[8];
#pragma unroll
  for (int j = 0; j < 8; ++j) {
    a[j] = conv_b[c + j];
    w[j] = *(const float4*)(conv_w + (c + j) * DCONV);
  }
#pragma unroll
  for (int k = 0; k < DCONV; ++k) {
    const int tt = t + k - (DCONV - 1);
    if (tt >= 0) {
      const u16x8 v = *(const u16x8*)(xz + ((size_t)(b * LSEQ + tt) << 12) + c);
#pragma unroll
      for (int j = 0; j < 8; ++j)
        a[j] = fmaf(bf2f(v[j]), ((const float*)&w[j])[k], a[j]);
    }
  }
  u16x8 o;
#pragma unroll
  for (int j = 0; j < 8; ++j) o[j] = f2bf(silu_f(a[j]));
  *(u16x8*)(xact + ((size_t)(b * LSEQ + t) << 11) + c) = o;
}

// ---- chunked parallel scan (exact decomposition of the linear recurrence) --

__global__ __launch_bounds__(256, 2)
void scan_pass1(const u16* __restrict__ dtb, const u16* __restrict__ xact,
                const float* __restrict__ A_log,
                float* __restrict__ hbuf, float* __restrict__ sumdt) {
  const int gid = blockIdx.x * 256 + threadIdx.x;  // 2^18 lanes
  const int c  = gid & (DINNER - 1);
  const int ch = (gid >> 11) & (NCH - 1);
  const int b  = gid >> 17;
  float a2[16];
#pragma unroll
  for (int s = 0; s < 16; ++s)
    a2[s] = -__expf(A_log[c * DSTATE + s]) * LOG2E;   // exp(dt*a) = exp2(dt*a2)
  const size_t base = ((size_t)(b * LSEQ + ch * LC) << 11) + c;
  float h[16] = {};
  float sd = 0.f;
  for (int j = 0; j < LC; j += 2) {
    const float dt0 = bf2f(dtb [base + ((size_t)j << 11)]);
    const float xv0 = bf2f(xact[base + ((size_t)j << 11)]);
    const float dt1 = bf2f(dtb [base + ((size_t)(j + 1) << 11)]);
    const float xv1 = bf2f(xact[base + ((size_t)(j + 1) << 11)]);
    const float dx0 = dt0 * xv0, dx1 = dt1 * xv1;
    sd += dt0 + dt1;
#pragma unroll
    for (int s = 0; s < 16; ++s)
      h[s] = fmaf(__builtin_amdgcn_exp2f(dt0 * a2[s]), h[s], dx0);
#pragma unroll
    for (int s = 0; s < 16; ++s)
      h[s] = fmaf(__builtin_amdgcn_exp2f(dt1 * a2[s]), h[s], dx1);
  }
  float4* ho = (float4*)&hbuf[(((size_t)(b * NCH + ch) * DINNER) + c) << 4];
#pragma unroll
  for (int q = 0; q < 4; ++q) {
    float4 v = { h[4 * q], h[4 * q + 1], h[4 * q + 2], h[4 * q + 3] };
    ho[q] = v;
  }
  sumdt[(size_t)(b * NCH + ch) * DINNER + c] = sd;
}

__global__ __launch_bounds__(256)
void scan_combine(float* __restrict__ hbuf, const float* __restrict__ sumdt,
                  const float* __restrict__ A_log) {
  const int gid = blockIdx.x * 256 + threadIdx.x;  // 2^16: b*32768 + c*16 + s
  const int s = gid & 15;
  const int c = (gid >> 4) & (DINNER - 1);
  const int b = gid >> 15;
  const float a2 = -__expf(A_log[c * DSTATE + s]) * LOG2E;
  float h = 0.f;
  for (int k = 0; k < NCH; ++k) {
    const size_t o = (((size_t)(b * NCH + k) * DINNER) + c) * 16 + s;
    const float he = hbuf[o];
    const float sd = sumdt[(size_t)(b * NCH + k) * DINNER + c];
    hbuf[o] = h;                          // h_start for chunk k
    h = fmaf(__builtin_amdgcn_exp2f(sd * a2), h, he);
  }
}

// Pass 3: re-scan from h_start; y = sum_s h + Dp*x; gate silu(z); bf16 rm out.
__global__ __launch_bounds__(256, 2)
void scan_pass3(const u16* __restrict__ dtb, const u16* __restrict__ xact,
                const u16* __restrict__ xz, const float* __restrict__ A_log,
                const float* __restrict__ Dp, const float* __restrict__ hbuf,
                u16* __restrict__ yg) {
  const int gid = blockIdx.x * 256 + threadIdx.x;
  const int c  = gid & (DINNER - 1);
  const int ch = (gid >> 11) & (NCH - 1);
  const int b  = gid >> 17;
  float a2[16];
#pragma unroll
  for (int s = 0; s < 16; ++s)
    a2[s] = -__expf(A_log[c * DSTATE + s]) * LOG2E;
  const float dp = Dp[c];
  float h[16];
  const float4* hi = (const float4*)&hbuf[(((size_t)(b * NCH + ch) * DINNER) + c) << 4];
#pragma unroll
  for (int q = 0; q < 4; ++q) {
    float4 v = hi[q];
    h[4 * q] = v.x; h[4 * q + 1] = v.y; h[4 * q + 2] = v.z; h[4 * q + 3] = v.w;
  }
  const size_t base  = ((size_t)(b * LSEQ + ch * LC) << 11) + c;
  const size_t zbase = ((size_t)(b * LSEQ + ch * LC) << 12) + DINNER + c;
  for (int j = 0; j < LC; j += 2) {
    const float dt0 = bf2f(dtb [base + ((size_t)j << 11)]);
    const float xv0 = bf2f(xact[base + ((size_t)j << 11)]);
    const float zv0 = bf2f(xz[zbase + ((size_t)j << 12)]);
    const float dt1 = bf2f(dtb [base + ((size_t)(j + 1) << 11)]);
    const float xv1 = bf2f(xact[base + ((size_t)(j + 1) << 11)]);
    const float zv1 = bf2f(xz[zbase + ((size_t)(j + 1) << 12)]);
    const float dx0 = dt0 * xv0, dx1 = dt1 * xv1;
    float y0 = 0.f, y1 = 0.f;
#pragma unroll
    for (int s = 0; s < 16; ++s) {
      h[s] = fmaf(__builtin_amdgcn_exp2f(dt0 * a2[s]), h[s], dx0);
      y0 += h[s];
    }
#pragma unroll
    for (int s = 0; s < 16; ++s) {
      h[s] = fmaf(__builtin_amdgcn_exp2f(dt1 * a2[s]), h[s], dx1);
      y1 += h[s];
    }
    y0 = fmaf(dp, xv0, y0);
    y1 = fmaf(dp, xv1, y1);
    yg[base + ((size_t)j << 11)]       = f2bf(y0 * silu_f(zv0));
    yg[base + ((size_t)(j + 1) << 11)] = f2bf(y1 * silu_f(zv1));
  }
}

extern "C" void kernel_launch(void* const* d_in, const int* in_sizes, int n_in,
                              void* d_out, int out_size, void* d_ws, size_t ws_size,
                              hipStream_t stream) {
  const float* x      = (const float*)d_in[0];
  const float* W_in   = (const float*)d_in[1];
  const float* conv_w = (const float*)d_in[2];
  const float* conv_b = (const float*)d_in[3];
  const float* A_log  = (const float*)d_in[4];
  const float* Dp     = (const float*)d_in[5];
  const float* W_dt   = (const float*)d_in[6];
  const float* b_dt   = (const float*)d_in[7];
  const float* W_out  = (const float*)d_in[8];
  float* out = (float*)d_out;

  // workspace layout (~133 MB)
  float* ws    = (float*)d_ws;
  float* hbuf  = ws;                                     // [B,NCH,D,16] f32 16 MB
  float* sumdt = hbuf + (size_t)BSZ * NCH * DINNER * 16; // 1 MB
  u16* xz   = (u16*)(sumdt + (size_t)BSZ * NCH * DINNER);// rm [4096,4096] 32 MB
  u16* dtb  = xz   + (size_t)MTOT * 2 * DINNER;          // rm [4096,2048] 16 MB
  u16* xbf  = dtb  + (size_t)MTOT * DINNER;              // x bf16          8 MB
  u16* wibf = xbf  + (size_t)MTOT * DMODEL;              // W_in bf16       8 MB
  u16* wdbf = wibf + (size_t)2 * DINNER * DMODEL;        // W_dt bf16       8 MB
  u16* wobf = wdbf + (size_t)DINNER * DINNER;            // W_out bf16      4 MB
  u16* xact = wobf + (size_t)DMODEL * DINNER;            // x_act bf16     16 MB
  u16* yg   = xact + (size_t)MTOT * DINNER;              // y_gated bf16   16 MB

  const dim3 blk(256);

  // 0) all casts in one dispatch
  const int n0 = MTOT * DMODEL / 4, n1 = 2 * DINNER * DMODEL / 4;
  const int n2 = DINNER * DINNER / 4, n3 = DMODEL * DINNER / 4;
  cast4<<<(n0 + n1 + n2 + n3) / 256, blk, 0, stream>>>(
      (const float4*)x, (ushort4*)xbf, n0,
      (const float4*)W_in, (ushort4*)wibf, n1,
      (const float4*)W_dt, (ushort4*)wdbf, n2,
      (const float4*)W_out, (ushort4*)wobf, n3);

  // 1) xz = x @ W_in^T (bf16 out)
  hgemm64<0, 1><<<(MTOT / 128) * (2 * DINNER / 128), blk, 0, stream>>>(
      xbf, wibf, nullptr, xz, MTOT, 2 * DINNER, DMODEL);
  // 2) x_act = silu(conv(x_proj) + conv_b), bf16
  conv_silu<<<(MTOT * 256) / 256, blk, 0, stream>>>(xz, conv_w, conv_b, xact);
  // 3) dt = softplus(x_act @ W_dt^T + b_dt), bf16 out
  hgemm64<1, 1><<<(MTOT / 128) * (DINNER / 128), blk, 0, stream>>>(
      xact, wdbf, b_dt, dtb, MTOT, DINNER, DINNER);
  // 4) chunked selective scan + D skip + gate
  scan_pass1<<<BSZ * NCH * DINNER / 256, blk, 0, stream>>>(dtb, xact, A_log, hbuf, sumdt);
  scan_combine<<<BSZ * DINNER * 16 / 256, blk, 0, stream>>>(hbuf, sumdt, A_log);
  scan_pass3<<<BSZ * NCH * DINNER / 256, blk, 0, stream>>>(dtb, xact, xz, A_log, Dp, hbuf, yg);
  // 5) out = y_gated @ W_out^T (fp32 out)
  hgemm64<0, 0><<<(MTOT / 128) * (DMODEL / 128), blk, 0, stream>>>(
      yg, wobf, nullptr, out, MTOT, DMODEL, DINNER);
}